// Round 4
// baseline (236.828 us; speedup 1.0000x reference)
//
#include <hip/hip_runtime.h>
#include <math.h>

// FeatureSpecExtractor: per-(b,f) EMA-normalize over time.
//   s_t = 0.95*s_{t-1} + 0.05*|x_t|;  y_t = x_t / sqrt(s_t)
// spec: (16,1,257,8000) f32, use features 0..255. out: (16,1,256,8000) f32.
//
// Parallel via constant-coefficient linear-recurrence scan:
//   one block per row (4096 blocks), 500 threads x 16 contiguous elems.
//   Weighted Kogge-Stone wave scan with A = 0.95^16; cross-wave carry via
//   LDS (coupling 0.95^1024 ~ 1.5e-23).

#define ALPHA   0.95f
#define OMA     0.05f
#define TLEN    8000
#define CHUNK   16
#define NACT    500   // 500*16 = 8000

// A^o = 0.95^(16*o)
#define A16_1   0.44012666865f
#define A16_2   0.19371148547f
#define A16_4   0.03752413897f
#define A16_8   0.00140806094f
#define A16_16  1.98263565e-06f
#define A16_32  3.93084413e-12f
#define A1024   1.54515294e-23f   // 0.95^1024 (wave-to-wave carry factor)
#define LOG2_A16 (-1.18400927f)   // 16*log2(0.95)

__global__ __launch_bounds__(512) void fse_kernel(
    const float* __restrict__ spec,
    const float* __restrict__ uns,
    float* __restrict__ out)
{
    const int bf = blockIdx.x;            // 0..4095
    const int b  = bf >> 8;
    const int f  = bf & 255;
    const float* inrow  = spec + ((size_t)b * 257 + (size_t)f) * TLEN;
    float*       outrow = out  + ((size_t)bf) * TLEN;

    const int tid  = threadIdx.x;
    const int lane = tid & 63;
    const int w    = tid >> 6;
    const bool active = (tid < NACT);

    // ---- pass 1: load 16 contiguous floats, local zero-init scan -> d ----
    float4 xq[4];
    float d = 0.0f;
    if (active) {
        const float4* p = (const float4*)(inrow + tid * CHUNK);
#pragma unroll
        for (int i = 0; i < 4; ++i) xq[i] = p[i];
#pragma unroll
        for (int i = 0; i < 4; ++i) {
            d = fmaf(fabsf(xq[i].x), OMA, d * ALPHA);
            d = fmaf(fabsf(xq[i].y), OMA, d * ALPHA);
            d = fmaf(fabsf(xq[i].z), OMA, d * ALPHA);
            d = fmaf(fabsf(xq[i].w), OMA, d * ALPHA);
        }
    }

    // ---- wave-level weighted inclusive scan: v_k = sum_{j<=k} A^(k-j) d_j ----
    float v = d, t;
    t = __shfl_up(v, 1);  if (lane >= 1)  v = fmaf(A16_1,  t, v);
    t = __shfl_up(v, 2);  if (lane >= 2)  v = fmaf(A16_2,  t, v);
    t = __shfl_up(v, 4);  if (lane >= 4)  v = fmaf(A16_4,  t, v);
    t = __shfl_up(v, 8);  if (lane >= 8)  v = fmaf(A16_8,  t, v);
    t = __shfl_up(v, 16); if (lane >= 16) v = fmaf(A16_16, t, v);
    t = __shfl_up(v, 32); if (lane >= 32) v = fmaf(A16_32, t, v);

    // ---- cross-wave carry (8 waves) ----
    __shared__ float tot[8];
    if (lane == 63) tot[w] = v;
    __syncthreads();
    float carry = 0.0f;                   // = global inclusive at end of wave w-1
    for (int j = 0; j < w; ++j) carry = fmaf(carry, A1024, tot[j]);

    // exclusive scan value (global): E_k = incl_{k-1}
    float e = __shfl_up(v, 1);
    if (lane == 0) e = 0.0f;
    e = fmaf(exp2f(LOG2_A16 * (float)lane), carry, e);

    // incoming state for this thread's chunk
    const float s0 = uns[f];
    float s = fmaf(exp2f(LOG2_A16 * (float)tid), s0, e);

    // ---- pass 2: exact sequential recurrence over the 16 register values ----
    if (active) {
#pragma unroll
        for (int i = 0; i < 4; ++i) {
            s = fmaf(fabsf(xq[i].x), OMA, s * ALPHA); xq[i].x = xq[i].x * rsqrtf(s);
            s = fmaf(fabsf(xq[i].y), OMA, s * ALPHA); xq[i].y = xq[i].y * rsqrtf(s);
            s = fmaf(fabsf(xq[i].z), OMA, s * ALPHA); xq[i].z = xq[i].z * rsqrtf(s);
            s = fmaf(fabsf(xq[i].w), OMA, s * ALPHA); xq[i].w = xq[i].w * rsqrtf(s);
        }
        float4* q = (float4*)(outrow + tid * CHUNK);
#pragma unroll
        for (int i = 0; i < 4; ++i) q[i] = xq[i];
    }
}

extern "C" void kernel_launch(void* const* d_in, const int* in_sizes, int n_in,
                              void* d_out, int out_size, void* d_ws, size_t ws_size,
                              hipStream_t stream) {
    const float* spec = (const float*)d_in[0];
    const float* uns  = (const float*)d_in[1];
    float* out = (float*)d_out;
    (void)in_sizes; (void)n_in; (void)d_ws; (void)ws_size; (void)out_size;

    dim3 grid(16 * 256);   // one block per (b, f) row
    dim3 block(512);
    fse_kernel<<<grid, block, 0, stream>>>(spec, uns, out);
}

// Round 6
// 230.230 us; speedup vs baseline: 1.0287x; 1.0287x over previous
//
#include <hip/hip_runtime.h>
#include <math.h>

// FeatureSpecExtractor: per-(b,f) EMA-normalize over time.
//   s_t = 0.95*s_{t-1} + 0.05*|x_t|;  y_t = x_t / sqrt(s_t)
// spec: (16,1,257,8000) f32, features 0..255 used. out: (16,1,256,8000) f32.
//
// v2: fully-coalesced layout. One block per row; the row is split into
// 4 segments of 2000 floats. Thread t owns float4 chunk t of EACH segment
// (chunk = 4 floats => lane stride 16B => perfectly coalesced loads/stores).
// Each segment gets an independent weighted Kogge-Stone scan (A4 = 0.95^4);
// 0.95^2000 underflows f32, so inter-segment coupling is exactly one scalar
// (previous segment's final inclusive value), passed through LDS.

#define TLEN   8000
#define SEGLEN 2000
#define NCHUNK 500            // float4 chunks per segment
#define ALPHA  0.95f
#define OMA    0.05f

// A4 = 0.95^4 and its powers (Kogge-Stone step coefficients, distances 1..32)
#define A4_1   0.81450625f    // 0.95^4
#define A4_2   0.66342043f    // 0.95^8
#define A4_4   0.44012667f    // 0.95^16
#define A4_8   0.19371149f    // 0.95^32
#define A4_16  0.03752414f    // 0.95^64
#define A4_32  0.00140806f    // 0.95^128
#define A256   1.98263565e-06f // 0.95^256: wave->wave carry factor (64 chunks)
#define LOG2_A4 (-0.29600231f) // 4*log2(0.95)

__global__ __launch_bounds__(512) void fse_kernel(
    const float* __restrict__ spec,
    const float* __restrict__ uns,
    float* __restrict__ out)
{
    const int bf = blockIdx.x;            // 0..4095
    const int b  = bf >> 8;
    const int f  = bf & 255;
    const float* inrow  = spec + ((size_t)b * 257 + (size_t)f) * TLEN;
    float*       outrow = out  + ((size_t)bf) * TLEN;

    const int tid  = threadIdx.x;
    const int lane = tid & 63;
    const int w    = tid >> 6;            // wave id 0..7
    const bool active = (tid < NCHUNK);

    // ---- coalesced loads: one float4 per segment ----
    float4 xq[4];
#pragma unroll
    for (int k = 0; k < 4; ++k) {
        if (active)
            xq[k] = *(const float4*)(inrow + k * SEGLEN + tid * 4);
    }

    // ---- local (zero-init) chunk scans: d[k] = sum a^(3-i)*0.05*|x_i| ----
    float v[4];
#pragma unroll
    for (int k = 0; k < 4; ++k) {
        float d = 0.0f;
        if (active) {
            d = fmaf(fabsf(xq[k].x), OMA, d * ALPHA);
            d = fmaf(fabsf(xq[k].y), OMA, d * ALPHA);
            d = fmaf(fabsf(xq[k].z), OMA, d * ALPHA);
            d = fmaf(fabsf(xq[k].w), OMA, d * ALPHA);
        }
        v[k] = d;
    }

    // ---- 4 interleaved weighted Kogge-Stone scans across the wave ----
#define SCAN_STEP(D, C)                                                \
    {                                                                  \
        float t0 = __shfl_up(v[0], D);                                 \
        float t1 = __shfl_up(v[1], D);                                 \
        float t2 = __shfl_up(v[2], D);                                 \
        float t3 = __shfl_up(v[3], D);                                 \
        if (lane >= D) {                                               \
            v[0] = fmaf(C, t0, v[0]);                                  \
            v[1] = fmaf(C, t1, v[1]);                                  \
            v[2] = fmaf(C, t2, v[2]);                                  \
            v[3] = fmaf(C, t3, v[3]);                                  \
        }                                                              \
    }
    SCAN_STEP(1,  A4_1)
    SCAN_STEP(2,  A4_2)
    SCAN_STEP(4,  A4_4)
    SCAN_STEP(8,  A4_8)
    SCAN_STEP(16, A4_16)
    SCAN_STEP(32, A4_32)
#undef SCAN_STEP

    // ---- cross-wave carries (per segment) ----
    __shared__ float tot[4][8];
    __shared__ float segend[4];
    if (lane == 63) {
#pragma unroll
        for (int k = 0; k < 4; ++k) tot[k][w] = v[k];
    }
    __syncthreads();

    const float pl = exp2f(LOG2_A4 * (float)lane);   // A4^lane
    float e[4];
#pragma unroll
    for (int k = 0; k < 4; ++k) {
        float carry = 0.0f;                          // incl. value at end of wave w-1
        for (int j = 0; j < w; ++j) carry = fmaf(carry, A256, tot[k][j]);
        float ex = __shfl_up(v[k], 1);
        if (lane == 0) ex = 0.0f;
        e[k] = fmaf(pl, carry, ex);                  // global exclusive (data part)
        // thread 499: full inclusive at segment end -> seed for next segment
        if (tid == NCHUNK - 1 && k < 3)
            segend[k] = fmaf(pl * A4_1, carry, v[k]);  // A4^(lane+1) * carry + v
    }
    __syncthreads();

    // ---- per-chunk incoming state, then exact 4-step recurrence + store ----
    const float pt = exp2f(LOG2_A4 * (float)tid);    // A4^tid (underflow->0 ok)
    const float s0 = uns[f];
    float S0[4];
    S0[0] = s0;
    S0[1] = segend[0];
    S0[2] = segend[1];
    S0[3] = segend[2];   // 0.95^2000 * S0 underflows: seed is exactly segend

#pragma unroll
    for (int k = 0; k < 4; ++k) {
        if (active) {
            float s = fmaf(pt, S0[k], e[k]);
            float4 r = xq[k];
            s = fmaf(fabsf(r.x), OMA, s * ALPHA); r.x = r.x * rsqrtf(s);
            s = fmaf(fabsf(r.y), OMA, s * ALPHA); r.y = r.y * rsqrtf(s);
            s = fmaf(fabsf(r.z), OMA, s * ALPHA); r.z = r.z * rsqrtf(s);
            s = fmaf(fabsf(r.w), OMA, s * ALPHA); r.w = r.w * rsqrtf(s);
            *(float4*)(outrow + k * SEGLEN + tid * 4) = r;
        }
    }
}

extern "C" void kernel_launch(void* const* d_in, const int* in_sizes, int n_in,
                              void* d_out, int out_size, void* d_ws, size_t ws_size,
                              hipStream_t stream) {
    const float* spec = (const float*)d_in[0];
    const float* uns  = (const float*)d_in[1];
    float* out = (float*)d_out;
    (void)in_sizes; (void)n_in; (void)d_ws; (void)ws_size; (void)out_size;

    dim3 grid(16 * 256);   // one block per (b, f) row
    dim3 block(512);
    fse_kernel<<<grid, block, 0, stream>>>(spec, uns, out);
}